// Round 12
// baseline (140.350 us; speedup 1.0000x reference)
//
#include <hip/hip_runtime.h>
#include <hip/hip_bf16.h>
#include <stdint.h>

#define MODS 7
#define NMOD 1024
#define EMOD 32768
#define NN (MODS*NMOD)   // 7168 nodes
#define EE (MODS*EMOD)   // 229376 edges
#define KC2 4            // block-level key chunks for self-attention
#define G1B (MODS*16*4)  // gemm1 blocks (RT=64) in fused launch
#define NCHUNK 32        // k_comb chunks per module

typedef __hip_bfloat16 bf16;

static __device__ __forceinline__ float lrelu(float x){ return x > 0.f ? x : 0.2f*x; }
static __device__ __forceinline__ float bfu(unsigned short u){ return __uint_as_float(((unsigned)u) << 16); }
static __device__ __forceinline__ float2 f2fma(float2 a, float2 b, float2 c){
  return make_float2(fmaf(a.x,b.x,c.x), fmaf(a.y,b.y,c.y));
}

// ---------------- per-module SGEMM body; optional bf16 out; fused GAT scores; optional QKV-transpose store ----------------
template<int K, int JT, bool TB, int RT, bool OBF, int SC, bool TRQ>
__device__ __forceinline__ void gemm_body(int b, const float* __restrict__ A,
    const float* __restrict__ B, const float* __restrict__ bias, void* __restrict__ Cv,
    const float* __restrict__ a_s, const float* __restrict__ a_d,
    float* __restrict__ es, float* __restrict__ ed) {
  constexpr int jt = JT/64;
  constexpr int rtiles = NMOD/RT;
  constexpr int RPT = RT/16;
  int ct = b % jt; b /= jt;
  int rt = b % rtiles; b /= rtiles;
  int m = b;
  int row0 = m*NMOD + rt*RT;
  int col0 = ct*64;
  __shared__ float Ast[32][RT+4];  // transposed: [kk][row]
  __shared__ float Bs[32][68];
  float acc[RPT][4] = {};
  int tid = threadIdx.x;
  int tr = (tid >> 4) * RPT;
  int tc = (tid & 15) * 4;
  const float* Bm = B + (size_t)m*K*JT;
  for (int k0 = 0; k0 < K; k0 += 32) {
    if constexpr (RT >= 32) {
      constexpr int ANUM = RT*32/1024;
      #pragma unroll
      for (int i = 0; i < ANUM; ++i) {
        int it = tid + i*256;
        int rr = it >> 3, kk0 = (it & 7)*4;
        float4 t = *(const float4*)&A[(size_t)(row0+rr)*K + k0 + kk0];
        Ast[kk0+0][rr] = t.x; Ast[kk0+1][rr] = t.y; Ast[kk0+2][rr] = t.z; Ast[kk0+3][rr] = t.w;
      }
    } else { // RT == 16
      if (tid < 128) {
        int rr = tid >> 3, kk0 = (tid & 7)*4;
        float4 t = *(const float4*)&A[(size_t)(row0+rr)*K + k0 + kk0];
        Ast[kk0+0][rr] = t.x; Ast[kk0+1][rr] = t.y; Ast[kk0+2][rr] = t.z; Ast[kk0+3][rr] = t.w;
      }
    }
    #pragma unroll
    for (int i = 0; i < 2; ++i) {
      int it = tid + i*256;
      if (!TB) {
        int kk = it >> 4, jj0 = (it & 15)*4;
        float4 t = *(const float4*)&Bm[(size_t)(k0+kk)*JT + col0 + jj0];
        Bs[kk][jj0] = t.x; Bs[kk][jj0+1] = t.y; Bs[kk][jj0+2] = t.z; Bs[kk][jj0+3] = t.w;
      } else {
        int jj = it >> 3, kk0 = (it & 7)*4;
        float4 t = *(const float4*)&Bm[(size_t)(col0+jj)*K + k0 + kk0];
        Bs[kk0+0][jj] = t.x; Bs[kk0+1][jj] = t.y; Bs[kk0+2][jj] = t.z; Bs[kk0+3][jj] = t.w;
      }
    }
    __syncthreads();
    #pragma unroll
    for (int kk = 0; kk < 32; ++kk) {
      float4 bv = *(const float4*)&Bs[kk][tc];
      float av[RPT];
      if constexpr (RPT == 4) {
        float4 t = *(const float4*)&Ast[kk][tr];
        av[0] = t.x; av[1] = t.y; av[2] = t.z; av[3] = t.w;
      } else if constexpr (RPT == 2) {
        av[0] = Ast[kk][tr]; av[1] = Ast[kk][tr+1];
      } else {
        av[0] = Ast[kk][tr];
      }
      #pragma unroll
      for (int i = 0; i < RPT; ++i) {
        acc[i][0] += av[i]*bv.x; acc[i][1] += av[i]*bv.y;
        acc[i][2] += av[i]*bv.z; acc[i][3] += av[i]*bv.w;
      }
    }
    __syncthreads();
  }
  float4 bb = {0,0,0,0};
  if (bias) bb = *(const float4*)&bias[m*JT + col0 + tc];
  #pragma unroll
  for (int i = 0; i < RPT; ++i) {
    float4 o = { acc[i][0]+bb.x, acc[i][1]+bb.y, acc[i][2]+bb.z, acc[i][3]+bb.w };
    if constexpr (TRQ) {
      float* Cp = (float*)Cv;
      size_t idx = ((size_t)(m*3 + ct)*NMOD + (rt*RT + tr + i))*64 + tc;
      *(float4*)&Cp[idx] = o;
    } else {
      size_t idx = (size_t)(row0+tr+i)*JT + col0 + tc;
      if constexpr (OBF) {
        bf16* Cp = (bf16*)Cv;
        bf16 tmp[4] = { __float2bfloat16(o.x), __float2bfloat16(o.y),
                        __float2bfloat16(o.z), __float2bfloat16(o.w) };
        *(uint2*)&Cp[idx] = *(const uint2*)tmp;
      } else {
        float* Cp = (float*)Cv;
        *(float4*)&Cp[idx] = o;
      }
    }
  }
  if constexpr (SC == 4) {
    int hh = ct;
    float4 as4 = *(const float4*)&a_s[(m*4 + hh)*64 + tc];
    float4 ad4 = *(const float4*)&a_d[(m*4 + hh)*64 + tc];
    #pragma unroll
    for (int i = 0; i < RPT; ++i) {
      float s = acc[i][0]*as4.x + acc[i][1]*as4.y + acc[i][2]*as4.z + acc[i][3]*as4.w;
      float d = acc[i][0]*ad4.x + acc[i][1]*ad4.y + acc[i][2]*ad4.z + acc[i][3]*ad4.w;
      #pragma unroll
      for (int off = 1; off < 16; off <<= 1) { s += __shfl_xor(s, off); d += __shfl_xor(d, off); }
      if ((tid & 15) == 0) {
        es[(row0+tr+i)*4 + hh] = s;
        ed[(row0+tr+i)*4 + hh] = d;
      }
    }
  }
  if constexpr (SC == 1) {
    float4 as4 = *(const float4*)&a_s[m*64 + tc];
    float4 ad4 = *(const float4*)&a_d[m*64 + tc];
    float s = acc[0][0]*as4.x + acc[0][1]*as4.y + acc[0][2]*as4.z + acc[0][3]*as4.w;
    float d = acc[0][0]*ad4.x + acc[0][1]*ad4.y + acc[0][2]*ad4.z + acc[0][3]*ad4.w;
    #pragma unroll
    for (int off = 1; off < 16; off <<= 1) { s += __shfl_xor(s, off); d += __shfl_xor(d, off); }
    if ((tid & 15) == 0) { es[row0+tr] = s; ed[row0+tr] = d; }
  }
}

// ---------------- per-module CSR count+scan in LDS (one block per module) ----------------
__device__ __forceinline__ void hist_body(int mm, const int* __restrict__ dst,
                                          int* __restrict__ rs, int* __restrict__ rs2) {
  __shared__ int hc[NMOD];
  __shared__ int hws[4];
  int tid = threadIdx.x;
  hc[tid] = 0; hc[tid+256] = 0; hc[tid+512] = 0; hc[tid+768] = 0;
  __syncthreads();
  const int4* d4 = (const int4*)(dst + mm*EMOD);
  int base = mm*NMOD;
  for (int it = tid; it < EMOD/4; it += 256) {
    int4 d = d4[it];
    atomicAdd(&hc[d.x - base], 1); atomicAdd(&hc[d.y - base], 1);
    atomicAdd(&hc[d.z - base], 1); atomicAdd(&hc[d.w - base], 1);
  }
  __syncthreads();
  int lane = tid & 63, wid = tid >> 6;
  int i0 = tid*4;
  int v0 = hc[i0], v1 = hc[i0+1], v2 = hc[i0+2], v3 = hc[i0+3];
  int T = v0+v1+v2+v3;
  int X = T;
  #pragma unroll
  for (int off = 1; off < 64; off <<= 1) { int t = __shfl_up(X, off); if (lane >= off) X += t; }
  if (lane == 63) hws[wid] = X;
  __syncthreads();
  int woff = 0;
  #pragma unroll
  for (int w = 0; w < 4; ++w) if (w < wid) woff += hws[w];
  int ex = mm*EMOD + woff + X - T;
  int4 o = make_int4(ex, ex+v0, ex+v0+v1, ex+v0+v1+v2);
  *(int4*)&rs[base + i0]  = o;
  *(int4*)&rs2[base + i0] = o;
  if (mm == MODS-1 && tid == 255) rs[NN] = EE;
}

// ---------------- fused launch: GEMM1(+scores) || CSR hist ----------------
__global__ __launch_bounds__(256) void k_g1h(const float* __restrict__ x,
    const float* __restrict__ g1w, bf16* __restrict__ h1,
    const float* __restrict__ a_s, const float* __restrict__ a_d,
    float* __restrict__ es, float* __restrict__ ed,
    const int* __restrict__ dst, int* __restrict__ rs, int* __restrict__ rs2) {
  if (blockIdx.x < G1B)
    gemm_body<128,256,false,64,true,4,false>(blockIdx.x, x, g1w, nullptr, h1, a_s, a_d, es, ed);
  else
    hist_body(blockIdx.x - G1B, dst, rs, rs2);
}

// ---------------- GEMM2 + fused H=1 scores, bf16 h2 out ----------------
__global__ __launch_bounds__(256) void k_g2s(const float* __restrict__ A,
    const float* __restrict__ B, bf16* __restrict__ h2,
    const float* __restrict__ a_s, const float* __restrict__ a_d,
    float* __restrict__ es, float* __restrict__ ed) {
  gemm_body<256,64,false,16,true,1,false>(blockIdx.x, A, B, nullptr, h2, a_s, a_d, es, ed);
}

// ---------------- QKV GEMM with transposed [m][p][n][64] store (RT=64) ----------------
__global__ __launch_bounds__(256) void k_gqkv(const float* __restrict__ A,
    const float* __restrict__ B, const float* __restrict__ bias, float* __restrict__ C) {
  gemm_body<64,192,true,64,false,0,true>(blockIdx.x, A, B, bias, C, nullptr, nullptr, nullptr, nullptr);
}

// rs2 doubles as the fill cursor (rebuilt every call by hist_body); 4 edges/thread
__global__ void k_fill(const int* __restrict__ src, const int* __restrict__ dst,
                       int* __restrict__ rs2, int* __restrict__ csr_src) {
  int e4 = blockIdx.x*256 + threadIdx.x;
  if (e4 < EE/4) {
    int4 s = ((const int4*)src)[e4];
    int4 d = ((const int4*)dst)[e4];
    csr_src[atomicAdd(&rs2[d.x], 1)] = s.x;
    csr_src[atomicAdd(&rs2[d.y], 1)] = s.y;
    csr_src[atomicAdd(&rs2[d.z], 1)] = s.z;
    csr_src[atomicAdd(&rs2[d.w], 1)] = s.w;
  }
}

// ---------------- GAT layer-1 aggregation: one wave per node, all 4 heads, 16-wide ----------------
__global__ __launch_bounds__(256) void k_agg4(const bf16* __restrict__ h,
    const float* __restrict__ es, const float* __restrict__ ed, const int* __restrict__ rs,
    const int* __restrict__ csr_src, const float* __restrict__ bias, float* __restrict__ out) {
  int wid = __builtin_amdgcn_readfirstlane(threadIdx.x >> 6);
  int n = blockIdx.x*4 + wid;
  int lane = threadIdx.x & 63;
  int hh = lane >> 4;
  int m = n >> 10;
  const unsigned short* hp = (const unsigned short*)h;
  float edv = ed[n*4 + hh];
  float p0 = __expf(lrelu(es[n*4 + hh] + edv));   // self-loop
  float den = p0;
  ushort4 v0 = *(const ushort4*)&hp[(size_t)n*256 + lane*4];
  float a0 = p0*bfu(v0.x), a1 = p0*bfu(v0.y), a2 = p0*bfu(v0.z), a3 = p0*bfu(v0.w);
  int beg = rs[n], end = rs[n+1];
  int i = beg;
  for (; i + 16 <= end; i += 16) {
    int ss[16]; ushort4 ww[16]; float qq[16];
    #pragma unroll
    for (int k = 0; k < 16; ++k) ss[k] = csr_src[i+k];
    #pragma unroll
    for (int k = 0; k < 16; ++k) ww[k] = *(const ushort4*)&hp[(size_t)ss[k]*256 + lane*4];
    #pragma unroll
    for (int k = 0; k < 16; ++k) qq[k] = __expf(lrelu(es[ss[k]*4 + hh] + edv));
    #pragma unroll
    for (int k = 0; k < 16; ++k) {
      den += qq[k];
      a0 += qq[k]*bfu(ww[k].x); a1 += qq[k]*bfu(ww[k].y);
      a2 += qq[k]*bfu(ww[k].z); a3 += qq[k]*bfu(ww[k].w);
    }
  }
  for (; i + 4 <= end; i += 4) {
    int ss[4]; ushort4 ww[4]; float qq[4];
    #pragma unroll
    for (int k = 0; k < 4; ++k) ss[k] = csr_src[i+k];
    #pragma unroll
    for (int k = 0; k < 4; ++k) ww[k] = *(const ushort4*)&hp[(size_t)ss[k]*256 + lane*4];
    #pragma unroll
    for (int k = 0; k < 4; ++k) qq[k] = __expf(lrelu(es[ss[k]*4 + hh] + edv));
    #pragma unroll
    for (int k = 0; k < 4; ++k) {
      den += qq[k];
      a0 += qq[k]*bfu(ww[k].x); a1 += qq[k]*bfu(ww[k].y);
      a2 += qq[k]*bfu(ww[k].z); a3 += qq[k]*bfu(ww[k].w);
    }
  }
  for (; i < end; ++i) {
    int s = csr_src[i];
    ushort4 w = *(const ushort4*)&hp[(size_t)s*256 + lane*4];
    float q = __expf(lrelu(es[s*4 + hh] + edv));
    den += q;
    a0 += q*bfu(w.x); a1 += q*bfu(w.y); a2 += q*bfu(w.z); a3 += q*bfu(w.w);
  }
  float inv = 1.f/den;
  float4 bb = *(const float4*)&bias[m*256 + lane*4];
  float4 o = { fmaxf(a0*inv + bb.x, 0.f), fmaxf(a1*inv + bb.y, 0.f),
               fmaxf(a2*inv + bb.z, 0.f), fmaxf(a3*inv + bb.w, 0.f) };
  *(float4*)&out[(size_t)n*256 + lane*4] = o;
}

// ---------------- GAT layer-2 aggregation (H=1, per-node wave, 16-wide) ----------------
__global__ __launch_bounds__(256) void k_agg1(const bf16* __restrict__ h,
    const float* __restrict__ es, const float* __restrict__ ed, const int* __restrict__ rs,
    const int* __restrict__ csr_src, const float* __restrict__ bias, float* __restrict__ out) {
  int wid = __builtin_amdgcn_readfirstlane(threadIdx.x >> 6);
  int n = blockIdx.x*4 + wid;
  int lane = threadIdx.x & 63;
  int m = n >> 10;
  float edv = ed[n];
  float p0 = __expf(lrelu(es[n] + edv));
  float den = p0;
  float acc = p0 * __bfloat162float(h[(size_t)n*64 + lane]);
  int beg = rs[n], end = rs[n+1];
  int i = beg;
  for (; i + 16 <= end; i += 16) {
    int ss[16]; float vv[16]; float qq[16];
    #pragma unroll
    for (int k = 0; k < 16; ++k) ss[k] = csr_src[i+k];
    #pragma unroll
    for (int k = 0; k < 16; ++k) vv[k] = __bfloat162float(h[(size_t)ss[k]*64 + lane]);
    #pragma unroll
    for (int k = 0; k < 16; ++k) qq[k] = __expf(lrelu(es[ss[k]] + edv));
    #pragma unroll
    for (int k = 0; k < 16; ++k) { den += qq[k]; acc += qq[k]*vv[k]; }
  }
  for (; i + 4 <= end; i += 4) {
    int ss[4]; float vv[4]; float qq[4];
    #pragma unroll
    for (int k = 0; k < 4; ++k) ss[k] = csr_src[i+k];
    #pragma unroll
    for (int k = 0; k < 4; ++k) vv[k] = __bfloat162float(h[(size_t)ss[k]*64 + lane]);
    #pragma unroll
    for (int k = 0; k < 4; ++k) qq[k] = __expf(lrelu(es[ss[k]] + edv));
    #pragma unroll
    for (int k = 0; k < 4; ++k) { den += qq[k]; acc += qq[k]*vv[k]; }
  }
  for (; i < end; ++i) {
    int s = csr_src[i];
    float q = __expf(lrelu(es[s] + edv));
    den += q;
    acc += q * __bfloat162float(h[(size_t)s*64 + lane]);
  }
  float v = acc/den + bias[m*64 + lane];
  out[(size_t)n*64 + lane] = fmaxf(v, 0.f);
}

// ---------------- self-attention on transposed qkv [m][p][1024][64]; K AND V depth-1 prefetch ----------------
__global__ __launch_bounds__(256) void k_attn(const float* __restrict__ qkv,
    float* __restrict__ pd, float* __restrict__ pacc) {
  int b = blockIdx.x;
  int kcg = b & (KC2-1); b /= KC2;
  int h = b & 3; b >>= 2;
  int qt = b & 15; int m = b >> 4;
  int lane = threadIdx.x & 63;
  int wu = __builtin_amdgcn_readfirstlane(threadIdx.x >> 6);
  int nl = qt*64 + lane;                // local node
  int n = m*NMOD + nl;
  float2 q2[8];
  const float* qrow = qkv + ((size_t)(m*3 + 0)*NMOD + nl)*64 + h*16;
  #pragma unroll
  for (int c = 0; c < 4; ++c) {
    float4 t = *(const float4*)(qrow + 4*c);
    q2[2*c]   = make_float2(t.x*0.25f, t.y*0.25f);
    q2[2*c+1] = make_float2(t.z*0.25f, t.w*0.25f);
  }
  int k0 = kcg*256 + wu*64;             // this wave's 64 keys
  const float* kb = qkv + ((size_t)(m*3 + 1)*NMOD + k0)*64 + h*16;
  const float* vb = qkv + ((size_t)(m*3 + 2)*NMOD + k0)*64 + h*16;
  float den = 0.f;
  float2 acc2[8] = {};
  float2 kreg[8], vreg[8];
  #pragma unroll
  for (int c = 0; c < 8; ++c) { kreg[c] = ((const float2*)kb)[c]; vreg[c] = ((const float2*)vb)[c]; }
  for (int j = 0; j < 64; ++j) {
    // prefetch next K and V rows (j=63 overreads next region — stays inside workspace)
    const float2* nk = (const float2*)(kb + (size_t)(j+1)*64);
    const float2* nv = (const float2*)(vb + (size_t)(j+1)*64);
    float2 knx[8], vnx[8];
    #pragma unroll
    for (int c = 0; c < 8; ++c) { knx[c] = nk[c]; vnx[c] = nv[c]; }
    float2 d0 = {0,0}, d1 = {0,0};
    #pragma unroll
    for (int c = 0; c < 8; c += 2) { d0 = f2fma(q2[c], kreg[c], d0); d1 = f2fma(q2[c+1], kreg[c+1], d1); }
    float p = __expf((d0.x + d0.y) + (d1.x + d1.y));
    den += p;
    float2 pp = {p, p};
    #pragma unroll
    for (int c = 0; c < 8; ++c) acc2[c] = f2fma(pp, vreg[c], acc2[c]);
    #pragma unroll
    for (int c = 0; c < 8; ++c) { kreg[c] = knx[c]; vreg[c] = vnx[c]; }
  }
  __shared__ float red[4][64][17];
  #pragma unroll
  for (int c = 0; c < 8; ++c) { red[wu][lane][2*c] = acc2[c].x; red[wu][lane][2*c+1] = acc2[c].y; }
  red[wu][lane][16] = den;
  __syncthreads();
  if (wu == 0) {
    size_t o = ((size_t)n*4 + h)*KC2 + kcg;
    pd[o] = red[0][lane][16] + red[1][lane][16] + red[2][lane][16] + red[3][lane][16];
    #pragma unroll
    for (int c = 0; c < 16; ++c)
      pacc[o*16 + c] = red[0][lane][c] + red[1][lane][c] + red[2][lane][c] + red[3][lane][c];
  }
}

// ---------------- combine + partial node-mean (224 blocks: 7 modules x 32 chunks of 32 nodes) ----------------
__global__ __launch_bounds__(256) void k_comb(const float* __restrict__ pd,
    const float* __restrict__ pacc, float* __restrict__ partial) {
  int m = blockIdx.x >> 5, chunk = blockIdx.x & 31;
  __shared__ float part[4][64];
  int tid = threadIdx.x;
  int j = tid & 63, pp = tid >> 6;
  int h = j >> 4, c = j & 15;
  float s = 0.f;
  int base = m*NMOD + chunk*32;
  #pragma unroll 4
  for (int i = pp*8; i < pp*8 + 8; ++i) {
    int n = base + i;
    size_t o = ((size_t)n*4 + h)*KC2;
    float den = pd[o] + pd[o+1] + pd[o+2] + pd[o+3];
    float t = pacc[o*16 + c] + pacc[(o+1)*16 + c] + pacc[(o+2)*16 + c] + pacc[(o+3)*16 + c];
    s += t/den;
  }
  part[pp][j] = s;
  __syncthreads();
  if (pp == 0) partial[(size_t)blockIdx.x*64 + j] = part[0][j]+part[1][j]+part[2][j]+part[3][j];
}

// ---------------- reps reduction + out-proj + cross-attention + fusion + classifier (single block) ----------------
__global__ __launch_bounds__(256) void k_final(const float* __restrict__ partial,
    const float* __restrict__ out_w, const float* __restrict__ out_b,
    const float* __restrict__ ca_in_w, const float* __restrict__ ca_in_b,
    const float* __restrict__ ca_out_w, const float* __restrict__ ca_out_b,
    const float* __restrict__ fusion_w, const float* __restrict__ fc_w,
    const float* __restrict__ fc_b, const float* __restrict__ c1_w,
    const float* __restrict__ c1_b, const float* __restrict__ c2_w,
    const float* __restrict__ c2_b, float* __restrict__ dout) {
  __shared__ float PR[7][64];
  __shared__ float R[7][64];
  __shared__ float QKV[7][192];
  __shared__ float SC[4][7][8];
  __shared__ float AL[4][7][8];
  __shared__ float O[7][64];
  __shared__ float CR[7][64];
  __shared__ float W[8];
  __shared__ float part[4][64];
  __shared__ float FU[64];
  __shared__ float HM[32];
  int tid = threadIdx.x, lane = tid & 63;
  // Phase 0a: reduce partial[224][64] -> PR (node-mean)
  {
    int j = tid & 63, g = tid >> 6;
    for (int m = g; m < 7; m += 4) {
      float s = 0.f;
      #pragma unroll
      for (int k = 0; k < NCHUNK; ++k) s += partial[(size_t)(m*NCHUNK + k)*64 + j];
      PR[m][j] = s * (1.f/NMOD);
    }
  }
  __syncthreads();
  // Phase 0b: R = PR @ out_w^T + out_b (folded MHA out-projection); writes Output 1
  {
    int sub = tid & 3, tt0 = tid >> 2;
    #pragma unroll
    for (int it = 0; it < 7; ++it) {
      int t = tt0 + it*64;
      int qi = t >> 6, j = t & 63;
      const float4* wr = (const float4*)&out_w[((size_t)qi*64 + j)*64 + sub*16];
      const float4* rr = (const float4*)&PR[qi][sub*16];
      float s = 0.f;
      #pragma unroll
      for (int c = 0; c < 4; ++c) {
        float4 a = rr[c], w4 = wr[c];
        s += a.x*w4.x + a.y*w4.y + a.z*w4.z + a.w*w4.w;
      }
      s += __shfl_xor(s, 1); s += __shfl_xor(s, 2);
      if (sub == 0) {
        float r = s + out_b[qi*64 + j];
        R[qi][j] = r;
        dout[2 + qi*64 + j] = r;     // Output 1
      }
    }
  }
  __syncthreads();
  // Phase A: QKV = R @ ca_in_w^T + b
  {
    int sub = tid & 3, tt0 = tid >> 2;
    #pragma unroll 3
    for (int it = 0; it < 21; ++it) {
      int t = tt0 + it*64;
      int r = t/192, j = t - r*192;
      const float4* wr = (const float4*)&ca_in_w[j*64 + sub*16];
      const float4* rr = (const float4*)&R[r][sub*16];
      float s = 0.f;
      #pragma unroll
      for (int c = 0; c < 4; ++c) {
        float4 a = rr[c], w4 = wr[c];
        s += a.x*w4.x + a.y*w4.y + a.z*w4.z + a.w*w4.w;
      }
      s += __shfl_xor(s, 1); s += __shfl_xor(s, 2);
      if (sub == 0) QKV[r][j] = s + ca_in_b[j];
    }
    if (tid == 252) {
      float p[7]; float den = 0.f;
      #pragma unroll
      for (int i = 0; i < 7; ++i) { p[i] = __expf(fusion_w[i]); den += p[i]; }
      float inv = 1.f/den;
      #pragma unroll
      for (int i = 0; i < 7; ++i) W[i] = p[i]*inv;
    }
  }
  __syncthreads();
  // Phase B: 196 (h,q,k) score exps
  if (tid < 196) {
    int hh = tid/49, rem = tid - hh*49, qi = rem/7, ki = rem - qi*7;
    float s = 0.f;
    #pragma unroll
    for (int c = 0; c < 16; ++c) s += QKV[qi][hh*16 + c]*QKV[ki][64 + hh*16 + c];
    SC[hh][qi][ki] = __expf(s*0.25f);
  }
  __syncthreads();
  if (tid < 28) {
    int hh = tid/7, qi = tid - hh*7;
    float den = 0.f;
    #pragma unroll
    for (int k = 0; k < 7; ++k) den += SC[hh][qi][k];
    float inv = 1.f/den;
    #pragma unroll
    for (int k = 0; k < 7; ++k) AL[hh][qi][k] = SC[hh][qi][k]*inv;
  }
  __syncthreads();
  // Phase C: O = alpha @ V
  for (int i = tid; i < 448; i += 256) {
    int qi = i >> 6, j = i & 63, hh = j >> 4;
    float s = 0.f;
    #pragma unroll
    for (int k = 0; k < 7; ++k) s += AL[hh][qi][k]*QKV[k][128 + j];
    O[qi][j] = s;
  }
  __syncthreads();
  // Phase D: CR = O @ ca_out_w^T + b
  {
    int sub = tid & 3, tt0 = tid >> 2;
    #pragma unroll
    for (int it = 0; it < 7; ++it) {
      int t = tt0 + it*64;
      int qi = t >> 6, j = t & 63;
      const float4* wr = (const float4*)&ca_out_w[j*64 + sub*16];
      const float4* orow = (const float4*)&O[qi][sub*16];
      float s = 0.f;
      #pragma unroll
      for (int c = 0; c < 4; ++c) {
        float4 a = orow[c], w4 = wr[c];
        s += a.x*w4.x + a.y*w4.y + a.z*w4.z + a.w*w4.w;
      }
      s += __shfl_xor(s, 1); s += __shfl_xor(s, 2);
      if (sub == 0) CR[qi][j] = s + ca_out_b[j];
    }
  }
  __syncthreads();
  // Phase F: fused fusion-weight + fc
  {
    int w = tid >> 6;
    float s = 0.f;
    #pragma unroll 4
    for (int i = w*112; i < w*112 + 112; ++i)
      s += CR[i>>6][i&63]*W[i>>6]*fc_w[(size_t)i*64 + lane];
    part[w][lane] = s;
  }
  __syncthreads();
  if (tid < 64) FU[tid] = part[0][tid] + part[1][tid] + part[2][tid] + part[3][tid] + fc_b[tid];
  __syncthreads();
  // Phase G: HM = relu(FU @ c1_w + b)
  if (tid < 128) {
    int sub = tid & 3, j = tid >> 2;
    float s = 0.f;
    #pragma unroll
    for (int c = 0; c < 16; ++c) { int k = sub*16 + c; s += FU[k]*c1_w[k*32 + j]; }
    s += __shfl_xor(s, 1); s += __shfl_xor(s, 2);
    if (sub == 0) HM[j] = fmaxf(s + c1_b[j], 0.f);
  }
  __syncthreads();
  if (tid < 2) {
    float s = c2_b[tid];
    #pragma unroll
    for (int k = 0; k < 32; ++k) s += HM[k]*c2_w[k*2 + tid];
    dout[tid] = s;              // Output 0
  }
}

extern "C" void kernel_launch(void* const* d_in, const int* in_sizes, int n_in,
                              void* d_out, int out_size, void* d_ws, size_t ws_size,
                              hipStream_t stream) {
  (void)in_sizes; (void)n_in; (void)out_size; (void)ws_size;
  const float* x       = (const float*)d_in[0];
  const int*   ei      = (const int*)d_in[1];
  const float* g1_w    = (const float*)d_in[3];
  const float* g1_as   = (const float*)d_in[4];
  const float* g1_ad   = (const float*)d_in[5];
  const float* g1_b    = (const float*)d_in[6];
  const float* g2_w    = (const float*)d_in[7];
  const float* g2_as   = (const float*)d_in[8];
  const float* g2_ad   = (const float*)d_in[9];
  const float* g2_b    = (const float*)d_in[10];
  const float* sa_in_w = (const float*)d_in[11];
  const float* sa_in_b = (const float*)d_in[12];
  const float* sa_out_w= (const float*)d_in[13];
  const float* sa_out_b= (const float*)d_in[14];
  const float* ca_in_w = (const float*)d_in[15];
  const float* ca_in_b = (const float*)d_in[16];
  const float* ca_out_w= (const float*)d_in[17];
  const float* ca_out_b= (const float*)d_in[18];
  const float* fusion_w= (const float*)d_in[19];
  const float* fc_w    = (const float*)d_in[20];
  const float* fc_b    = (const float*)d_in[21];
  const float* c1_w    = (const float*)d_in[22];
  const float* c1_b    = (const float*)d_in[23];
  const float* c2_w    = (const float*)d_in[24];
  const float* c2_b    = (const float*)d_in[25];
  float* dout = (float*)d_out;

  const int* src = ei;        // edge_index[0]
  const int* dst = ei + EE;   // edge_index[1]

  // ---- workspace carve (aliasing by lifetime) ----
  char* p = (char*)d_ws;
  int* rs      = (int*)p; p += (size_t)(NN+4)*sizeof(int);
  int* rs2     = (int*)p; p += (size_t)(NN+4)*sizeof(int);
  int* csr_src = (int*)p; p += (size_t)EE*sizeof(int);
  p = (char*)(((uintptr_t)p + 255) & ~(uintptr_t)255);
  float* h1f  = (float*)p; p += (size_t)NN*256*4;   // bf16 h1; later qkv (f32, NN*192)
  float* es1  = (float*)p; p += (size_t)NN*4*4;
  float* ed1  = (float*)p; p += (size_t)NN*4*4;
  float* gat1 = (float*)p; p += (size_t)NN*256*4;   // later: pacc (NN*4*KC2*16 f32)
  float* h2f  = (float*)p; p += (size_t)NN*64*4;    // bf16 h2
  float* es2  = (float*)p; p += (size_t)NN*4;
  float* ed2  = (float*)p; p += (size_t)NN*4;
  float* z    = (float*)p; p += (size_t)NN*64*4;
  float* pdbuf= (float*)p; p += (size_t)NN*4*KC2*4; // pd (NN*4*KC2 f32)
  float* partial = (float*)p; p += (size_t)MODS*NCHUNK*64*4;
  bf16* h1    = (bf16*)h1f;
  bf16* h2    = (bf16*)h2f;
  float* qkv  = h1f;                 // h1 dead after k_agg4
  float* pacc = gat1;                // gat1 dead after k_g2s
  float* pd   = pdbuf;

  // K1: GEMM1 (+fused layer-1 scores, RT=64) || per-module CSR count+scan
  k_g1h<<<G1B + MODS, 256, 0, stream>>>(x, g1_w, h1, g1_as, g1_ad, es1, ed1, dst, rs, rs2);
  // K2: CSR fill (rs2 = cursors), 4 edges/thread
  k_fill<<<(EE/4+255)/256, 256, 0, stream>>>(src, dst, rs2, csr_src);
  // K3: GAT layer-1 aggregation (16-wide)
  k_agg4<<<NN/4, 256, 0, stream>>>(h1, es1, ed1, rs, csr_src, g1_b, gat1);
  // K4: GEMM2 + fused layer-2 scores (bf16 h2)
  k_g2s<<<MODS*64, 256, 0, stream>>>(gat1, g2_w, h2, g2_as, g2_ad, es2, ed2);
  // K5: GAT layer-2 aggregation (16-wide)
  k_agg1<<<NN/4, 256, 0, stream>>>(h2, es2, ed2, rs, csr_src, g2_b, z);
  // K6: QKV projection (transposed store, RT=64)
  k_gqkv<<<MODS*16*3, 256, 0, stream>>>(z, sa_in_w, sa_in_b, qkv);
  // K7: self-attention partials (KC2=4 -> 1792 blocks, K+V prefetch)
  k_attn<<<MODS*16*4*KC2, 256, 0, stream>>>(qkv, pd, pacc);
  // K8: combine + partial mean (224 blocks)
  k_comb<<<MODS*NCHUNK, 256, 0, stream>>>(pd, pacc, partial);
  // K9: reps reduction + out-proj + head (Outputs 0 and 1)
  k_final<<<1, 256, 0, stream>>>(partial, sa_out_w, sa_out_b,
                                 ca_in_w, ca_in_b, ca_out_w, ca_out_b,
                                 fusion_w, fc_w, fc_b, c1_w, c1_b, c2_w, c2_b, dout);
}

// Round 13
// 136.155 us; speedup vs baseline: 1.0308x; 1.0308x over previous
//
#include <hip/hip_runtime.h>
#include <hip/hip_bf16.h>
#include <stdint.h>

#define MODS 7
#define NMOD 1024
#define EMOD 32768
#define NN (MODS*NMOD)   // 7168 nodes
#define EE (MODS*EMOD)   // 229376 edges
#define KC2 4            // block-level key chunks for self-attention
#define G1B (MODS*16*4)  // gemm1 blocks (RT=64) in fused launch
#define NCHUNK 32        // k_comb chunks per module

typedef __hip_bfloat16 bf16;

static __device__ __forceinline__ float lrelu(float x){ return x > 0.f ? x : 0.2f*x; }
static __device__ __forceinline__ float bfu(unsigned short u){ return __uint_as_float(((unsigned)u) << 16); }
static __device__ __forceinline__ float2 f2fma(float2 a, float2 b, float2 c){
  return make_float2(fmaf(a.x,b.x,c.x), fmaf(a.y,b.y,c.y));
}

// ---------------- per-module SGEMM body; optional bf16 out; fused GAT scores; optional QKV-transpose store ----------------
template<int K, int JT, bool TB, int RT, bool OBF, int SC, bool TRQ>
__device__ __forceinline__ void gemm_body(int b, const float* __restrict__ A,
    const float* __restrict__ B, const float* __restrict__ bias, void* __restrict__ Cv,
    const float* __restrict__ a_s, const float* __restrict__ a_d,
    float* __restrict__ es, float* __restrict__ ed) {
  constexpr int jt = JT/64;
  constexpr int rtiles = NMOD/RT;
  constexpr int RPT = RT/16;
  int ct = b % jt; b /= jt;
  int rt = b % rtiles; b /= rtiles;
  int m = b;
  int row0 = m*NMOD + rt*RT;
  int col0 = ct*64;
  __shared__ float Ast[32][RT+4];  // transposed: [kk][row]
  __shared__ float Bs[32][68];
  float acc[RPT][4] = {};
  int tid = threadIdx.x;
  int tr = (tid >> 4) * RPT;
  int tc = (tid & 15) * 4;
  const float* Bm = B + (size_t)m*K*JT;
  for (int k0 = 0; k0 < K; k0 += 32) {
    if constexpr (RT >= 32) {
      constexpr int ANUM = RT*32/1024;
      #pragma unroll
      for (int i = 0; i < ANUM; ++i) {
        int it = tid + i*256;
        int rr = it >> 3, kk0 = (it & 7)*4;
        float4 t = *(const float4*)&A[(size_t)(row0+rr)*K + k0 + kk0];
        Ast[kk0+0][rr] = t.x; Ast[kk0+1][rr] = t.y; Ast[kk0+2][rr] = t.z; Ast[kk0+3][rr] = t.w;
      }
    } else { // RT == 16
      if (tid < 128) {
        int rr = tid >> 3, kk0 = (tid & 7)*4;
        float4 t = *(const float4*)&A[(size_t)(row0+rr)*K + k0 + kk0];
        Ast[kk0+0][rr] = t.x; Ast[kk0+1][rr] = t.y; Ast[kk0+2][rr] = t.z; Ast[kk0+3][rr] = t.w;
      }
    }
    #pragma unroll
    for (int i = 0; i < 2; ++i) {
      int it = tid + i*256;
      if (!TB) {
        int kk = it >> 4, jj0 = (it & 15)*4;
        float4 t = *(const float4*)&Bm[(size_t)(k0+kk)*JT + col0 + jj0];
        Bs[kk][jj0] = t.x; Bs[kk][jj0+1] = t.y; Bs[kk][jj0+2] = t.z; Bs[kk][jj0+3] = t.w;
      } else {
        int jj = it >> 3, kk0 = (it & 7)*4;
        float4 t = *(const float4*)&Bm[(size_t)(col0+jj)*K + k0 + kk0];
        Bs[kk0+0][jj] = t.x; Bs[kk0+1][jj] = t.y; Bs[kk0+2][jj] = t.z; Bs[kk0+3][jj] = t.w;
      }
    }
    __syncthreads();
    #pragma unroll
    for (int kk = 0; kk < 32; ++kk) {
      float4 bv = *(const float4*)&Bs[kk][tc];
      float av[RPT];
      if constexpr (RPT == 4) {
        float4 t = *(const float4*)&Ast[kk][tr];
        av[0] = t.x; av[1] = t.y; av[2] = t.z; av[3] = t.w;
      } else if constexpr (RPT == 2) {
        av[0] = Ast[kk][tr]; av[1] = Ast[kk][tr+1];
      } else {
        av[0] = Ast[kk][tr];
      }
      #pragma unroll
      for (int i = 0; i < RPT; ++i) {
        acc[i][0] += av[i]*bv.x; acc[i][1] += av[i]*bv.y;
        acc[i][2] += av[i]*bv.z; acc[i][3] += av[i]*bv.w;
      }
    }
    __syncthreads();
  }
  float4 bb = {0,0,0,0};
  if (bias) bb = *(const float4*)&bias[m*JT + col0 + tc];
  #pragma unroll
  for (int i = 0; i < RPT; ++i) {
    float4 o = { acc[i][0]+bb.x, acc[i][1]+bb.y, acc[i][2]+bb.z, acc[i][3]+bb.w };
    if constexpr (TRQ) {
      float* Cp = (float*)Cv;
      size_t idx = ((size_t)(m*3 + ct)*NMOD + (rt*RT + tr + i))*64 + tc;
      *(float4*)&Cp[idx] = o;
    } else {
      size_t idx = (size_t)(row0+tr+i)*JT + col0 + tc;
      if constexpr (OBF) {
        bf16* Cp = (bf16*)Cv;
        bf16 tmp[4] = { __float2bfloat16(o.x), __float2bfloat16(o.y),
                        __float2bfloat16(o.z), __float2bfloat16(o.w) };
        *(uint2*)&Cp[idx] = *(const uint2*)tmp;
      } else {
        float* Cp = (float*)Cv;
        *(float4*)&Cp[idx] = o;
      }
    }
  }
  if constexpr (SC == 4) {
    int hh = ct;
    float4 as4 = *(const float4*)&a_s[(m*4 + hh)*64 + tc];
    float4 ad4 = *(const float4*)&a_d[(m*4 + hh)*64 + tc];
    #pragma unroll
    for (int i = 0; i < RPT; ++i) {
      float s = acc[i][0]*as4.x + acc[i][1]*as4.y + acc[i][2]*as4.z + acc[i][3]*as4.w;
      float d = acc[i][0]*ad4.x + acc[i][1]*ad4.y + acc[i][2]*ad4.z + acc[i][3]*ad4.w;
      #pragma unroll
      for (int off = 1; off < 16; off <<= 1) { s += __shfl_xor(s, off); d += __shfl_xor(d, off); }
      if ((tid & 15) == 0) {
        es[(row0+tr+i)*4 + hh] = s;
        ed[(row0+tr+i)*4 + hh] = d;
      }
    }
  }
  if constexpr (SC == 1) {
    float4 as4 = *(const float4*)&a_s[m*64 + tc];
    float4 ad4 = *(const float4*)&a_d[m*64 + tc];
    float s = acc[0][0]*as4.x + acc[0][1]*as4.y + acc[0][2]*as4.z + acc[0][3]*as4.w;
    float d = acc[0][0]*ad4.x + acc[0][1]*ad4.y + acc[0][2]*ad4.z + acc[0][3]*ad4.w;
    #pragma unroll
    for (int off = 1; off < 16; off <<= 1) { s += __shfl_xor(s, off); d += __shfl_xor(d, off); }
    if ((tid & 15) == 0) { es[row0+tr] = s; ed[row0+tr] = d; }
  }
}

// ---------------- per-module CSR count+scan in LDS (one block per module) ----------------
__device__ __forceinline__ void hist_body(int mm, const int* __restrict__ dst,
                                          int* __restrict__ rs, int* __restrict__ rs2) {
  __shared__ int hc[NMOD];
  __shared__ int hws[4];
  int tid = threadIdx.x;
  hc[tid] = 0; hc[tid+256] = 0; hc[tid+512] = 0; hc[tid+768] = 0;
  __syncthreads();
  const int4* d4 = (const int4*)(dst + mm*EMOD);
  int base = mm*NMOD;
  for (int it = tid; it < EMOD/4; it += 256) {
    int4 d = d4[it];
    atomicAdd(&hc[d.x - base], 1); atomicAdd(&hc[d.y - base], 1);
    atomicAdd(&hc[d.z - base], 1); atomicAdd(&hc[d.w - base], 1);
  }
  __syncthreads();
  int lane = tid & 63, wid = tid >> 6;
  int i0 = tid*4;
  int v0 = hc[i0], v1 = hc[i0+1], v2 = hc[i0+2], v3 = hc[i0+3];
  int T = v0+v1+v2+v3;
  int X = T;
  #pragma unroll
  for (int off = 1; off < 64; off <<= 1) { int t = __shfl_up(X, off); if (lane >= off) X += t; }
  if (lane == 63) hws[wid] = X;
  __syncthreads();
  int woff = 0;
  #pragma unroll
  for (int w = 0; w < 4; ++w) if (w < wid) woff += hws[w];
  int ex = mm*EMOD + woff + X - T;
  int4 o = make_int4(ex, ex+v0, ex+v0+v1, ex+v0+v1+v2);
  *(int4*)&rs[base + i0]  = o;
  *(int4*)&rs2[base + i0] = o;
  if (mm == MODS-1 && tid == 255) rs[NN] = EE;
}

// ---------------- fused launch: GEMM1(+scores) || CSR hist ----------------
__global__ __launch_bounds__(256) void k_g1h(const float* __restrict__ x,
    const float* __restrict__ g1w, bf16* __restrict__ h1,
    const float* __restrict__ a_s, const float* __restrict__ a_d,
    float* __restrict__ es, float* __restrict__ ed,
    const int* __restrict__ dst, int* __restrict__ rs, int* __restrict__ rs2) {
  if (blockIdx.x < G1B)
    gemm_body<128,256,false,64,true,4,false>(blockIdx.x, x, g1w, nullptr, h1, a_s, a_d, es, ed);
  else
    hist_body(blockIdx.x - G1B, dst, rs, rs2);
}

// ---------------- GEMM2 + fused H=1 scores, bf16 h2 out ----------------
__global__ __launch_bounds__(256) void k_g2s(const float* __restrict__ A,
    const float* __restrict__ B, bf16* __restrict__ h2,
    const float* __restrict__ a_s, const float* __restrict__ a_d,
    float* __restrict__ es, float* __restrict__ ed) {
  gemm_body<256,64,false,16,true,1,false>(blockIdx.x, A, B, nullptr, h2, a_s, a_d, es, ed);
}

// ---------------- QKV GEMM with transposed [m][p][n][64] store (RT=64) ----------------
__global__ __launch_bounds__(256) void k_gqkv(const float* __restrict__ A,
    const float* __restrict__ B, const float* __restrict__ bias, float* __restrict__ C) {
  gemm_body<64,192,true,64,false,0,true>(blockIdx.x, A, B, bias, C, nullptr, nullptr, nullptr, nullptr);
}

// rs2 doubles as the fill cursor (rebuilt every call by hist_body); 4 edges/thread
__global__ void k_fill(const int* __restrict__ src, const int* __restrict__ dst,
                       int* __restrict__ rs2, int* __restrict__ csr_src) {
  int e4 = blockIdx.x*256 + threadIdx.x;
  if (e4 < EE/4) {
    int4 s = ((const int4*)src)[e4];
    int4 d = ((const int4*)dst)[e4];
    csr_src[atomicAdd(&rs2[d.x], 1)] = s.x;
    csr_src[atomicAdd(&rs2[d.y], 1)] = s.y;
    csr_src[atomicAdd(&rs2[d.z], 1)] = s.z;
    csr_src[atomicAdd(&rs2[d.w], 1)] = s.w;
  }
}

// ---------------- GAT layer-1 aggregation: one wave per node, all 4 heads, 16-wide ----------------
__global__ __launch_bounds__(256) void k_agg4(const bf16* __restrict__ h,
    const float* __restrict__ es, const float* __restrict__ ed, const int* __restrict__ rs,
    const int* __restrict__ csr_src, const float* __restrict__ bias, float* __restrict__ out) {
  int wid = __builtin_amdgcn_readfirstlane(threadIdx.x >> 6);
  int n = blockIdx.x*4 + wid;
  int lane = threadIdx.x & 63;
  int hh = lane >> 4;
  int m = n >> 10;
  const unsigned short* hp = (const unsigned short*)h;
  float edv = ed[n*4 + hh];
  float p0 = __expf(lrelu(es[n*4 + hh] + edv));   // self-loop
  float den = p0;
  ushort4 v0 = *(const ushort4*)&hp[(size_t)n*256 + lane*4];
  float a0 = p0*bfu(v0.x), a1 = p0*bfu(v0.y), a2 = p0*bfu(v0.z), a3 = p0*bfu(v0.w);
  int beg = rs[n], end = rs[n+1];
  int i = beg;
  for (; i + 16 <= end; i += 16) {
    int ss[16]; ushort4 ww[16]; float qq[16];
    #pragma unroll
    for (int k = 0; k < 16; ++k) ss[k] = csr_src[i+k];
    #pragma unroll
    for (int k = 0; k < 16; ++k) ww[k] = *(const ushort4*)&hp[(size_t)ss[k]*256 + lane*4];
    #pragma unroll
    for (int k = 0; k < 16; ++k) qq[k] = __expf(lrelu(es[ss[k]*4 + hh] + edv));
    #pragma unroll
    for (int k = 0; k < 16; ++k) {
      den += qq[k];
      a0 += qq[k]*bfu(ww[k].x); a1 += qq[k]*bfu(ww[k].y);
      a2 += qq[k]*bfu(ww[k].z); a3 += qq[k]*bfu(ww[k].w);
    }
  }
  for (; i + 4 <= end; i += 4) {
    int ss[4]; ushort4 ww[4]; float qq[4];
    #pragma unroll
    for (int k = 0; k < 4; ++k) ss[k] = csr_src[i+k];
    #pragma unroll
    for (int k = 0; k < 4; ++k) ww[k] = *(const ushort4*)&hp[(size_t)ss[k]*256 + lane*4];
    #pragma unroll
    for (int k = 0; k < 4; ++k) qq[k] = __expf(lrelu(es[ss[k]*4 + hh] + edv));
    #pragma unroll
    for (int k = 0; k < 4; ++k) {
      den += qq[k];
      a0 += qq[k]*bfu(ww[k].x); a1 += qq[k]*bfu(ww[k].y);
      a2 += qq[k]*bfu(ww[k].z); a3 += qq[k]*bfu(ww[k].w);
    }
  }
  for (; i < end; ++i) {
    int s = csr_src[i];
    ushort4 w = *(const ushort4*)&hp[(size_t)s*256 + lane*4];
    float q = __expf(lrelu(es[s*4 + hh] + edv));
    den += q;
    a0 += q*bfu(w.x); a1 += q*bfu(w.y); a2 += q*bfu(w.z); a3 += q*bfu(w.w);
  }
  float inv = 1.f/den;
  float4 bb = *(const float4*)&bias[m*256 + lane*4];
  float4 o = { fmaxf(a0*inv + bb.x, 0.f), fmaxf(a1*inv + bb.y, 0.f),
               fmaxf(a2*inv + bb.z, 0.f), fmaxf(a3*inv + bb.w, 0.f) };
  *(float4*)&out[(size_t)n*256 + lane*4] = o;
}

// ---------------- GAT layer-2 aggregation (H=1, per-node wave, 16-wide) ----------------
__global__ __launch_bounds__(256) void k_agg1(const bf16* __restrict__ h,
    const float* __restrict__ es, const float* __restrict__ ed, const int* __restrict__ rs,
    const int* __restrict__ csr_src, const float* __restrict__ bias, float* __restrict__ out) {
  int wid = __builtin_amdgcn_readfirstlane(threadIdx.x >> 6);
  int n = blockIdx.x*4 + wid;
  int lane = threadIdx.x & 63;
  int m = n >> 10;
  float edv = ed[n];
  float p0 = __expf(lrelu(es[n] + edv));
  float den = p0;
  float acc = p0 * __bfloat162float(h[(size_t)n*64 + lane]);
  int beg = rs[n], end = rs[n+1];
  int i = beg;
  for (; i + 16 <= end; i += 16) {
    int ss[16]; float vv[16]; float qq[16];
    #pragma unroll
    for (int k = 0; k < 16; ++k) ss[k] = csr_src[i+k];
    #pragma unroll
    for (int k = 0; k < 16; ++k) vv[k] = __bfloat162float(h[(size_t)ss[k]*64 + lane]);
    #pragma unroll
    for (int k = 0; k < 16; ++k) qq[k] = __expf(lrelu(es[ss[k]] + edv));
    #pragma unroll
    for (int k = 0; k < 16; ++k) { den += qq[k]; acc += qq[k]*vv[k]; }
  }
  for (; i + 4 <= end; i += 4) {
    int ss[4]; float vv[4]; float qq[4];
    #pragma unroll
    for (int k = 0; k < 4; ++k) ss[k] = csr_src[i+k];
    #pragma unroll
    for (int k = 0; k < 4; ++k) vv[k] = __bfloat162float(h[(size_t)ss[k]*64 + lane]);
    #pragma unroll
    for (int k = 0; k < 4; ++k) qq[k] = __expf(lrelu(es[ss[k]] + edv));
    #pragma unroll
    for (int k = 0; k < 4; ++k) { den += qq[k]; acc += qq[k]*vv[k]; }
  }
  for (; i < end; ++i) {
    int s = csr_src[i];
    float q = __expf(lrelu(es[s] + edv));
    den += q;
    acc += q * __bfloat162float(h[(size_t)s*64 + lane]);
  }
  float v = acc/den + bias[m*64 + lane];
  out[(size_t)n*64 + lane] = fmaxf(v, 0.f);
}

// ---------------- self-attention on transposed qkv [m][p][1024][64]; batch-4 K/V staging ----------------
__global__ __launch_bounds__(256) void k_attn(const float* __restrict__ qkv,
    float* __restrict__ pd, float* __restrict__ pacc) {
  int b = blockIdx.x;
  int kcg = b & (KC2-1); b /= KC2;
  int h = b & 3; b >>= 2;
  int qt = b & 15; int m = b >> 4;
  int lane = threadIdx.x & 63;
  int wu = __builtin_amdgcn_readfirstlane(threadIdx.x >> 6);
  int nl = qt*64 + lane;                // local node
  int n = m*NMOD + nl;
  float2 q2[8];
  const float* qrow = qkv + ((size_t)(m*3 + 0)*NMOD + nl)*64 + h*16;
  #pragma unroll
  for (int c = 0; c < 4; ++c) {
    float4 t = *(const float4*)(qrow + 4*c);
    q2[2*c]   = make_float2(t.x*0.25f, t.y*0.25f);
    q2[2*c+1] = make_float2(t.z*0.25f, t.w*0.25f);
  }
  int k0 = kcg*256 + wu*64;             // this wave's 64 keys
  const float* kb = qkv + ((size_t)(m*3 + 1)*NMOD + k0)*64 + h*16;
  const float* vb = qkv + ((size_t)(m*3 + 2)*NMOD + k0)*64 + h*16;
  float den = 0.f;
  float2 acc2[8] = {};
  for (int jb = 0; jb < 64; jb += 4) {
    // stage 4 K rows + 4 V rows: 16 independent loads in flight before first use
    float2 kr[4][8], vr[4][8];
    #pragma unroll
    for (int r = 0; r < 4; ++r) {
      const float2* kp = (const float2*)(kb + (size_t)(jb+r)*64);
      const float2* vp = (const float2*)(vb + (size_t)(jb+r)*64);
      #pragma unroll
      for (int c = 0; c < 8; ++c) { kr[r][c] = kp[c]; vr[r][c] = vp[c]; }
    }
    #pragma unroll
    for (int r = 0; r < 4; ++r) {
      float2 d0 = {0,0}, d1 = {0,0};
      #pragma unroll
      for (int c = 0; c < 8; c += 2) { d0 = f2fma(q2[c], kr[r][c], d0); d1 = f2fma(q2[c+1], kr[r][c+1], d1); }
      float p = __expf((d0.x + d0.y) + (d1.x + d1.y));
      den += p;
      float2 pp = {p, p};
      #pragma unroll
      for (int c = 0; c < 8; ++c) acc2[c] = f2fma(pp, vr[r][c], acc2[c]);
    }
  }
  __shared__ float red[4][64][17];
  #pragma unroll
  for (int c = 0; c < 8; ++c) { red[wu][lane][2*c] = acc2[c].x; red[wu][lane][2*c+1] = acc2[c].y; }
  red[wu][lane][16] = den;
  __syncthreads();
  if (wu == 0) {
    size_t o = ((size_t)n*4 + h)*KC2 + kcg;
    pd[o] = red[0][lane][16] + red[1][lane][16] + red[2][lane][16] + red[3][lane][16];
    #pragma unroll
    for (int c = 0; c < 16; ++c)
      pacc[o*16 + c] = red[0][lane][c] + red[1][lane][c] + red[2][lane][c] + red[3][lane][c];
  }
}

// ---------------- combine + partial node-mean (224 blocks: 7 modules x 32 chunks of 32 nodes) ----------------
__global__ __launch_bounds__(256) void k_comb(const float* __restrict__ pd,
    const float* __restrict__ pacc, float* __restrict__ partial) {
  int m = blockIdx.x >> 5, chunk = blockIdx.x & 31;
  __shared__ float part[4][64];
  int tid = threadIdx.x;
  int j = tid & 63, pp = tid >> 6;
  int h = j >> 4, c = j & 15;
  float s = 0.f;
  int base = m*NMOD + chunk*32;
  #pragma unroll 4
  for (int i = pp*8; i < pp*8 + 8; ++i) {
    int n = base + i;
    size_t o = ((size_t)n*4 + h)*KC2;
    float den = pd[o] + pd[o+1] + pd[o+2] + pd[o+3];
    float t = pacc[o*16 + c] + pacc[(o+1)*16 + c] + pacc[(o+2)*16 + c] + pacc[(o+3)*16 + c];
    s += t/den;
  }
  part[pp][j] = s;
  __syncthreads();
  if (pp == 0) partial[(size_t)blockIdx.x*64 + j] = part[0][j]+part[1][j]+part[2][j]+part[3][j];
}

// ---------------- reps reduction + out-proj + cross-attention + fusion + classifier (single block) ----------------
__global__ __launch_bounds__(256) void k_final(const float* __restrict__ partial,
    const float* __restrict__ out_w, const float* __restrict__ out_b,
    const float* __restrict__ ca_in_w, const float* __restrict__ ca_in_b,
    const float* __restrict__ ca_out_w, const float* __restrict__ ca_out_b,
    const float* __restrict__ fusion_w, const float* __restrict__ fc_w,
    const float* __restrict__ fc_b, const float* __restrict__ c1_w,
    const float* __restrict__ c1_b, const float* __restrict__ c2_w,
    const float* __restrict__ c2_b, float* __restrict__ dout) {
  __shared__ float PR[7][64];
  __shared__ float R[7][64];
  __shared__ float QKV[7][192];
  __shared__ float SC[4][7][8];
  __shared__ float AL[4][7][8];
  __shared__ float O[7][64];
  __shared__ float CR[7][64];
  __shared__ float W[8];
  __shared__ float part[4][64];
  __shared__ float FU[64];
  __shared__ float HM[32];
  int tid = threadIdx.x, lane = tid & 63;
  // Phase 0a: reduce partial[224][64] -> PR (node-mean)
  {
    int j = tid & 63, g = tid >> 6;
    for (int m = g; m < 7; m += 4) {
      float s = 0.f;
      #pragma unroll
      for (int k = 0; k < NCHUNK; ++k) s += partial[(size_t)(m*NCHUNK + k)*64 + j];
      PR[m][j] = s * (1.f/NMOD);
    }
  }
  __syncthreads();
  // Phase 0b: R = PR @ out_w^T + out_b (folded MHA out-projection); writes Output 1
  {
    int sub = tid & 3, tt0 = tid >> 2;
    #pragma unroll
    for (int it = 0; it < 7; ++it) {
      int t = tt0 + it*64;
      int qi = t >> 6, j = t & 63;
      const float4* wr = (const float4*)&out_w[((size_t)qi*64 + j)*64 + sub*16];
      const float4* rr = (const float4*)&PR[qi][sub*16];
      float s = 0.f;
      #pragma unroll
      for (int c = 0; c < 4; ++c) {
        float4 a = rr[c], w4 = wr[c];
        s += a.x*w4.x + a.y*w4.y + a.z*w4.z + a.w*w4.w;
      }
      s += __shfl_xor(s, 1); s += __shfl_xor(s, 2);
      if (sub == 0) {
        float r = s + out_b[qi*64 + j];
        R[qi][j] = r;
        dout[2 + qi*64 + j] = r;     // Output 1
      }
    }
  }
  __syncthreads();
  // Phase A: QKV = R @ ca_in_w^T + b
  {
    int sub = tid & 3, tt0 = tid >> 2;
    #pragma unroll 3
    for (int it = 0; it < 21; ++it) {
      int t = tt0 + it*64;
      int r = t/192, j = t - r*192;
      const float4* wr = (const float4*)&ca_in_w[j*64 + sub*16];
      const float4* rr = (const float4*)&R[r][sub*16];
      float s = 0.f;
      #pragma unroll
      for (int c = 0; c < 4; ++c) {
        float4 a = rr[c], w4 = wr[c];
        s += a.x*w4.x + a.y*w4.y + a.z*w4.z + a.w*w4.w;
      }
      s += __shfl_xor(s, 1); s += __shfl_xor(s, 2);
      if (sub == 0) QKV[r][j] = s + ca_in_b[j];
    }
    if (tid == 252) {
      float p[7]; float den = 0.f;
      #pragma unroll
      for (int i = 0; i < 7; ++i) { p[i] = __expf(fusion_w[i]); den += p[i]; }
      float inv = 1.f/den;
      #pragma unroll
      for (int i = 0; i < 7; ++i) W[i] = p[i]*inv;
    }
  }
  __syncthreads();
  // Phase B: 196 (h,q,k) score exps
  if (tid < 196) {
    int hh = tid/49, rem = tid - hh*49, qi = rem/7, ki = rem - qi*7;
    float s = 0.f;
    #pragma unroll
    for (int c = 0; c < 16; ++c) s += QKV[qi][hh*16 + c]*QKV[ki][64 + hh*16 + c];
    SC[hh][qi][ki] = __expf(s*0.25f);
  }
  __syncthreads();
  if (tid < 28) {
    int hh = tid/7, qi = tid - hh*7;
    float den = 0.f;
    #pragma unroll
    for (int k = 0; k < 7; ++k) den += SC[hh][qi][k];
    float inv = 1.f/den;
    #pragma unroll
    for (int k = 0; k < 7; ++k) AL[hh][qi][k] = SC[hh][qi][k]*inv;
  }
  __syncthreads();
  // Phase C: O = alpha @ V
  for (int i = tid; i < 448; i += 256) {
    int qi = i >> 6, j = i & 63, hh = j >> 4;
    float s = 0.f;
    #pragma unroll
    for (int k = 0; k < 7; ++k) s += AL[hh][qi][k]*QKV[k][128 + j];
    O[qi][j] = s;
  }
  __syncthreads();
  // Phase D: CR = O @ ca_out_w^T + b
  {
    int sub = tid & 3, tt0 = tid >> 2;
    #pragma unroll
    for (int it = 0; it < 7; ++it) {
      int t = tt0 + it*64;
      int qi = t >> 6, j = t & 63;
      const float4* wr = (const float4*)&ca_out_w[j*64 + sub*16];
      const float4* orow = (const float4*)&O[qi][sub*16];
      float s = 0.f;
      #pragma unroll
      for (int c = 0; c < 4; ++c) {
        float4 a = orow[c], w4 = wr[c];
        s += a.x*w4.x + a.y*w4.y + a.z*w4.z + a.w*w4.w;
      }
      s += __shfl_xor(s, 1); s += __shfl_xor(s, 2);
      if (sub == 0) CR[qi][j] = s + ca_out_b[j];
    }
  }
  __syncthreads();
  // Phase F: fused fusion-weight + fc
  {
    int w = tid >> 6;
    float s = 0.f;
    #pragma unroll 4
    for (int i = w*112; i < w*112 + 112; ++i)
      s += CR[i>>6][i&63]*W[i>>6]*fc_w[(size_t)i*64 + lane];
    part[w][lane] = s;
  }
  __syncthreads();
  if (tid < 64) FU[tid] = part[0][tid] + part[1][tid] + part[2][tid] + part[3][tid] + fc_b[tid];
  __syncthreads();
  // Phase G: HM = relu(FU @ c1_w + b)
  if (tid < 128) {
    int sub = tid & 3, j = tid >> 2;
    float s = 0.f;
    #pragma unroll
    for (int c = 0; c < 16; ++c) { int k = sub*16 + c; s += FU[k]*c1_w[k*32 + j]; }
    s += __shfl_xor(s, 1); s += __shfl_xor(s, 2);
    if (sub == 0) HM[j] = fmaxf(s + c1_b[j], 0.f);
  }
  __syncthreads();
  if (tid < 2) {
    float s = c2_b[tid];
    #pragma unroll
    for (int k = 0; k < 32; ++k) s += HM[k]*c2_w[k*2 + tid];
    dout[tid] = s;              // Output 0
  }
}

extern "C" void kernel_launch(void* const* d_in, const int* in_sizes, int n_in,
                              void* d_out, int out_size, void* d_ws, size_t ws_size,
                              hipStream_t stream) {
  (void)in_sizes; (void)n_in; (void)out_size; (void)ws_size;
  const float* x       = (const float*)d_in[0];
  const int*   ei      = (const int*)d_in[1];
  const float* g1_w    = (const float*)d_in[3];
  const float* g1_as   = (const float*)d_in[4];
  const float* g1_ad   = (const float*)d_in[5];
  const float* g1_b    = (const float*)d_in[6];
  const float* g2_w    = (const float*)d_in[7];
  const float* g2_as   = (const float*)d_in[8];
  const float* g2_ad   = (const float*)d_in[9];
  const float* g2_b    = (const float*)d_in[10];
  const float* sa_in_w = (const float*)d_in[11];
  const float* sa_in_b = (const float*)d_in[12];
  const float* sa_out_w= (const float*)d_in[13];
  const float* sa_out_b= (const float*)d_in[14];
  const float* ca_in_w = (const float*)d_in[15];
  const float* ca_in_b = (const float*)d_in[16];
  const float* ca_out_w= (const float*)d_in[17];
  const float* ca_out_b= (const float*)d_in[18];
  const float* fusion_w= (const float*)d_in[19];
  const float* fc_w    = (const float*)d_in[20];
  const float* fc_b    = (const float*)d_in[21];
  const float* c1_w    = (const float*)d_in[22];
  const float* c1_b    = (const float*)d_in[23];
  const float* c2_w    = (const float*)d_in[24];
  const float* c2_b    = (const float*)d_in[25];
  float* dout = (float*)d_out;

  const int* src = ei;        // edge_index[0]
  const int* dst = ei + EE;   // edge_index[1]

  // ---- workspace carve (aliasing by lifetime) ----
  char* p = (char*)d_ws;
  int* rs      = (int*)p; p += (size_t)(NN+4)*sizeof(int);
  int* rs2     = (int*)p; p += (size_t)(NN+4)*sizeof(int);
  int* csr_src = (int*)p; p += (size_t)EE*sizeof(int);
  p = (char*)(((uintptr_t)p + 255) & ~(uintptr_t)255);
  float* h1f  = (float*)p; p += (size_t)NN*256*4;   // bf16 h1; later qkv (f32, NN*192)
  float* es1  = (float*)p; p += (size_t)NN*4*4;
  float* ed1  = (float*)p; p += (size_t)NN*4*4;
  float* gat1 = (float*)p; p += (size_t)NN*256*4;   // later: pacc (NN*4*KC2*16 f32)
  float* h2f  = (float*)p; p += (size_t)NN*64*4;    // bf16 h2
  float* es2  = (float*)p; p += (size_t)NN*4;
  float* ed2  = (float*)p; p += (size_t)NN*4;
  float* z    = (float*)p; p += (size_t)NN*64*4;
  float* pdbuf= (float*)p; p += (size_t)NN*4*KC2*4; // pd (NN*4*KC2 f32)
  float* partial = (float*)p; p += (size_t)MODS*NCHUNK*64*4;
  bf16* h1    = (bf16*)h1f;
  bf16* h2    = (bf16*)h2f;
  float* qkv  = h1f;                 // h1 dead after k_agg4
  float* pacc = gat1;                // gat1 dead after k_g2s
  float* pd   = pdbuf;

  // K1: GEMM1 (+fused layer-1 scores, RT=64) || per-module CSR count+scan
  k_g1h<<<G1B + MODS, 256, 0, stream>>>(x, g1_w, h1, g1_as, g1_ad, es1, ed1, dst, rs, rs2);
  // K2: CSR fill (rs2 = cursors), 4 edges/thread
  k_fill<<<(EE/4+255)/256, 256, 0, stream>>>(src, dst, rs2, csr_src);
  // K3: GAT layer-1 aggregation (16-wide)
  k_agg4<<<NN/4, 256, 0, stream>>>(h1, es1, ed1, rs, csr_src, g1_b, gat1);
  // K4: GEMM2 + fused layer-2 scores (bf16 h2)
  k_g2s<<<MODS*64, 256, 0, stream>>>(gat1, g2_w, h2, g2_as, g2_ad, es2, ed2);
  // K5: GAT layer-2 aggregation (16-wide)
  k_agg1<<<NN/4, 256, 0, stream>>>(h2, es2, ed2, rs, csr_src, g2_b, z);
  // K6: QKV projection (transposed store, RT=64)
  k_gqkv<<<MODS*16*3, 256, 0, stream>>>(z, sa_in_w, sa_in_b, qkv);
  // K7: self-attention partials (KC2=4 -> 1792 blocks, batch-4 staging)
  k_attn<<<MODS*16*4*KC2, 256, 0, stream>>>(qkv, pd, pacc);
  // K8: combine + partial mean (224 blocks)
  k_comb<<<MODS*NCHUNK, 256, 0, stream>>>(pd, pacc, partial);
  // K9: reps reduction + out-proj + head (Outputs 0 and 1)
  k_final<<<1, 256, 0, stream>>>(partial, sa_out_w, sa_out_b,
                                 ca_in_w, ca_in_b, ca_out_w, ca_out_b,
                                 fusion_w, fc_w, fc_b, c1_w, c1_b, c2_w, c2_b, dout);
}